// Round 4
// baseline (3042.162 us; speedup 1.0000x reference)
//
#include <hip/hip_runtime.h>
#include <hip/hip_bf16.h>

// SplineCNN block: 3x spline_conv (K=27, 8 active basis/edge) + ELU + BN.
// All scratch in __device__ statics referenced ONLY from device code
// (host-side mention of __device__ symbols gives the shadow address -> fault).
// Runtime bf16-vs-fp32 wire-dtype detection, dispatched per-load.

#define KW 27
#define EPS 1e-5f
#define MAXN 50176
#define MAXE 401408

__device__ int            g_deg[MAXN];
__device__ int            g_offs[MAXN + 1];
__device__ int            g_cursor[MAXN];
__device__ int            g_eidx[MAXE];
__device__ __hip_bfloat16 g_h1[MAXN * 32];
__device__ __hip_bfloat16 g_h2[MAXN * 64];
__device__ float          g_stats[128];
__device__ float          g_coef[128];
__device__ int            g_isbf16;

// flag-dispatched load of an external float tensor (bf16 or fp32 wire format)
__device__ __forceinline__ float loadf(const void* p, int i, bool bf)
{
    return bf ? (float)((const __hip_bfloat16*)p)[i] : ((const float*)p)[i];
}

// ---------------- wire dtype detection ----------------
// For packed bf16 pairs, the low 16 bits of each 32-bit word decode to a bf16
// of a ~N(0,1) sample -> biased exponent almost surely in [96,140]. For fp32,
// those bits are uniform mantissa bits -> ~18% hit rate. Threshold 200/256.
__global__ void detect_kernel(const unsigned int* __restrict__ w)
{
    int cnt = 0;
    for (int i = 0; i < 256; ++i) {
        unsigned int lo = w[i] & 0xFFFFu;
        int ex = (int)((lo >> 7) & 0xFFu);
        if (lo == 0u || (ex >= 96 && ex <= 140)) cnt++;
    }
    g_isbf16 = (cnt >= 200) ? 1 : 0;
}

// ---------------- zero-init scratch ----------------
__global__ void init_kernel(int n)
{
    int i = blockIdx.x * blockDim.x + threadIdx.x;
    if (i < n) { g_deg[i] = 0; g_cursor[i] = 0; }
    if (i < 128) g_stats[i] = 0.0f;
}

// ---------------- degree count ----------------
__global__ void count_kernel(const int* __restrict__ dst, int E)
{
    int e = blockIdx.x * blockDim.x + threadIdx.x;
    if (e >= E) return;
    atomicAdd(&g_deg[dst[e]], 1);
}

// ---------------- exclusive scan (single block, 1024 threads) ----------------
__global__ void scan_kernel(int n, int chunk)
{
    __shared__ int buf[1024];
    int tid = threadIdx.x;
    int begin = tid * chunk;
    int end = begin + chunk; if (end > n) end = n;
    int s = 0;
    for (int i = begin; i < end; ++i) s += g_deg[i];
    buf[tid] = s;
    __syncthreads();
    for (int o = 1; o < 1024; o <<= 1) {
        int t = (tid >= o) ? buf[tid - o] : 0;
        __syncthreads();
        buf[tid] += t;
        __syncthreads();
    }
    int base = buf[tid] - s;   // exclusive prefix of this chunk
    for (int i = begin; i < end; ++i) { g_offs[i] = base; base += g_deg[i]; }
    if (tid == 1023) g_offs[n] = buf[1023];
}

// ---------------- CSR fill ----------------
__global__ void fill_kernel(const int* __restrict__ dst, int E)
{
    int e = blockIdx.x * blockDim.x + threadIdx.x;
    if (e >= E) return;
    int d = dst[e];
    int p = atomicAdd(&g_cursor[d], 1);
    g_eidx[g_offs[d] + p] = e;
}

// ---------------- on-the-fly degree-1 closed B-spline basis ----------------
__device__ __forceinline__ void edge_basis(const void* __restrict__ attr, int e,
                                           bool bf, float bas[8], int wx[8])
{
    float f[3];
    int lo[3];
#pragma unroll
    for (int d = 0; d < 3; ++d) {
        float a = loadf(attr, e * 3 + d, bf);
        float s = a * 3.0f;
        float l = floorf(s);
        lo[d] = (int)l;
        f[d] = s - l;
    }
    const int p3[3] = {1, 3, 9};
#pragma unroll
    for (int b = 0; b < 8; ++b) {
        float w = 1.0f;
        int id = 0;
#pragma unroll
        for (int d = 0; d < 3; ++d) {
            int bit = (b >> d) & 1;
            w *= bit ? f[d] : (1.0f - f[d]);
            id += ((lo[d] + bit) % 3) * p3[d];
        }
        bas[b] = w;
        wx[b] = id;
    }
}

// ---------------- spline conv: one wave per node ----------------
// IN_SEL: 0 = external tensor x_in (wire dtype), 1 = g_h1 (bf16),
//         2 = concat(elu(bn(g_h2)), pos)  (pos = wire dtype)
// OUT_SEL: 0 = external out (wire dtype), 1 = g_h1, 2 = g_h2
template <int CIN, int COUT, bool ELU_OUT, int IN_SEL, int OUT_SEL>
__global__ __launch_bounds__(64) void conv_kernel(
    const void* __restrict__ x_in,
    const void* __restrict__ pos,
    const void* __restrict__ eattr,
    const int* __restrict__ src,
    const void* __restrict__ W, const void* __restrict__ root,
    const void* __restrict__ bias,
    void* __restrict__ out_ext)
{
    __shared__ float S[KW * CIN];
    __shared__ float xbuf[CIN];
    __shared__ float xself[CIN];
    __shared__ float Ab[64], Bb[64];
    int n = blockIdx.x;
    int tid = threadIdx.x;
    const bool bf = (g_isbf16 != 0);

    if (IN_SEL == 2) {
        Ab[tid] = g_coef[tid];
        Bb[tid] = g_coef[64 + tid];
    }
    for (int i = tid; i < KW * CIN; i += 64) S[i] = 0.0f;
    __syncthreads();

    auto load_in = [&](int node, int c) -> float {
        if (IN_SEL == 0) {
            return loadf(x_in, node * CIN + c, bf);
        } else if (IN_SEL == 1) {
            return (float)g_h1[node * CIN + c];
        } else {
            if (c < 64) {
                float v = (float)g_h2[node * 64 + c] * Ab[c] + Bb[c];
                return v > 0.0f ? v : expm1f(v);
            }
            return loadf(pos, node * 3 + (c - 64), bf);
        }
    };

    for (int i = tid; i < CIN; i += 64) xself[i] = load_in(n, i);
    int e0 = g_offs[n], e1 = g_offs[n + 1];
    __syncthreads();

    for (int ei = e0; ei < e1; ++ei) {
        int e = g_eidx[ei];
        int sidx = src[e];
        for (int i = tid; i < CIN; i += 64) xbuf[i] = load_in(sidx, i);
        __syncthreads();
        float bas[8];
        int wx[8];
        edge_basis(eattr, e, bf, bas, wx);
        // the 8 widx of one edge are pairwise distinct -> all 8*CIN targets distinct
        for (int idx = tid; idx < 8 * CIN; idx += 64) {
            int b = idx / CIN;
            int c = idx - b * CIN;
            S[wx[b] * CIN + c] += bas[b] * xbuf[c];
        }
        __syncthreads();
    }

    float degf = (float)(e1 - e0);
    if (degf < 1.0f) degf = 1.0f;
    float inv_deg = 1.0f / degf;

    for (int o = tid; o < COUT; o += 64) {
        float acc = 0.0f;
        for (int j = 0; j < KW * CIN; ++j)
            acc += S[j] * loadf(W, j * COUT + o, bf);
        acc *= inv_deg;
        float r = loadf(bias, o, bf);
        for (int i = 0; i < CIN; ++i)
            r += xself[i] * loadf(root, i * COUT + o, bf);
        acc += r;
        if (ELU_OUT) acc = acc > 0.0f ? acc : expm1f(acc);
        if (OUT_SEL == 1) {
            g_h1[n * COUT + o] = __float2bfloat16(acc);
        } else if (OUT_SEL == 2) {
            g_h2[n * COUT + o] = __float2bfloat16(acc);
        } else {
            if (bf) ((__hip_bfloat16*)out_ext)[n * COUT + o] = __float2bfloat16(acc);
            else    ((float*)out_ext)[n * COUT + o] = acc;
        }
    }
}

// ---------------- BN stats reduction (g_h2 bf16) ----------------
__global__ void bn_reduce(int n)
{
    int tid = threadIdx.x;
    int c = tid & 63;
    int r = tid >> 6;          // 4 rows of 64 channels
    float s = 0.0f, s2 = 0.0f;
    for (int i = blockIdx.x * 4 + r; i < n; i += gridDim.x * 4) {
        float v = (float)g_h2[i * 64 + c];
        s += v; s2 += v * v;
    }
    __shared__ float b1s[256], b2s[256];
    b1s[tid] = s; b2s[tid] = s2;
    __syncthreads();
    if (r == 0) {
        s  = b1s[c] + b1s[c + 64] + b1s[c + 128] + b1s[c + 192];
        s2 = b2s[c] + b2s[c + 64] + b2s[c + 128] + b2s[c + 192];
        atomicAdd(&g_stats[c], s);
        atomicAdd(&g_stats[64 + c], s2);
    }
}

// ---------------- BN coefficients: A = rstd*gamma, B = beta - mu*A ----------------
__global__ void bn_coef(const void* __restrict__ gamma,
                        const void* __restrict__ beta, int n)
{
    int c = threadIdx.x;   // 64
    const bool bf = (g_isbf16 != 0);
    float inv_n = 1.0f / (float)n;
    float mu = g_stats[c] * inv_n;
    float var = g_stats[64 + c] * inv_n - mu * mu;
    float A = rsqrtf(var + EPS) * loadf(gamma, c, bf);
    g_coef[c] = A;
    g_coef[64 + c] = loadf(beta, c, bf) - mu * A;
}

extern "C" void kernel_launch(void* const* d_in, const int* in_sizes, int n_in,
                              void* d_out, int out_size, void* d_ws, size_t ws_size,
                              hipStream_t stream)
{
    const void* x      = d_in[0];
    const int*  eindex = (const int*)d_in[1];
    const void* eattr  = d_in[2];
    const void* pos    = d_in[3];
    const void* W1     = d_in[4];
    const void* root1  = d_in[5];
    const void* b1     = d_in[6];
    const void* W2     = d_in[7];
    const void* root2  = d_in[8];
    const void* b2     = d_in[9];
    const void* gamma  = d_in[10];
    const void* beta   = d_in[11];
    const void* W3     = d_in[12];
    const void* root3  = d_in[13];
    const void* b3     = d_in[14];
    (void)d_ws; (void)ws_size; (void)n_in; (void)out_size;

    const int N = in_sizes[0] / 32;
    const int E = in_sizes[1] / 2;
    const int* srcp = eindex;
    const int* dstp = eindex + E;

    detect_kernel<<<1, 1, 0, stream>>>((const unsigned int*)x);
    init_kernel<<<(N + 255) / 256, 256, 0, stream>>>(N);

    int eb = (E + 255) / 256;
    count_kernel<<<eb, 256, 0, stream>>>(dstp, E);
    int chunk = (N + 1023) / 1024;
    scan_kernel<<<1, 1024, 0, stream>>>(N, chunk);
    fill_kernel<<<eb, 256, 0, stream>>>(dstp, E);

    // conv1: x(wire,32) -> g_h1(bf16,32), ELU
    conv_kernel<32, 32, true, 0, 1><<<N, 64, 0, stream>>>(
        x, nullptr, eattr, srcp, W1, root1, b1, nullptr);
    // conv2: g_h1(32) -> g_h2(64), raw (BN+ELU folded into conv3)
    conv_kernel<32, 64, false, 1, 2><<<N, 64, 0, stream>>>(
        nullptr, nullptr, eattr, srcp, W2, root2, b2, nullptr);
    // BN stats + affine coefficients
    bn_reduce<<<120, 256, 0, stream>>>(N);
    bn_coef<<<1, 64, 0, stream>>>(gamma, beta, N);
    // conv3: [elu(bn(h2)), pos](67) -> out(wire,32)
    conv_kernel<67, 32, false, 2, 0><<<N, 64, 0, stream>>>(
        nullptr, pos, eattr, srcp, W3, root3, b3, d_out);
}

// Round 5
// 640.986 us; speedup vs baseline: 4.7461x; 4.7461x over previous
//
#include <hip/hip_runtime.h>
#include <hip/hip_bf16.h>

// SplineCNN block via dense-Z factorization:
//   Z[s,k,o] = x[s]·W[k,:,o]  (k=0..26 spline kernels, k=27 root)  -- bf16 MFMA GEMM
//   C[n,o]   = (1/deg) Σ_{e->n} Σ_b bas_b · Z[src_e, wx_b, o] + Z[n,27,o] + bias[o]
// All scratch in __device__ statics (referenced only from device code).
// Runtime bf16-vs-fp32 wire dtype detection.

#define EPS 1e-5f
#define MAXN 50176
#define MAXE 401408

typedef __attribute__((ext_vector_type(8))) short short8;
typedef __attribute__((ext_vector_type(4))) float floatx4;

__device__ int             g_deg[MAXN];
__device__ int             g_offs[MAXN + 1];
__device__ int             g_cursor[MAXN];
__device__ int             g_eidx[MAXE];
__device__ float           g_basis[MAXE * 8];
__device__ unsigned char   g_widx[MAXE * 8];
__device__ __align__(16) __hip_bfloat16 g_h0[MAXN * 32];
__device__ __align__(16) __hip_bfloat16 g_h1[MAXN * 32];
__device__ __align__(16) __hip_bfloat16 g_h2[MAXN * 64];
__device__ __align__(16) __hip_bfloat16 g_h3[MAXN * 96];
__device__ __align__(16) __hip_bfloat16 g_Z[(size_t)MAXN * 1792];
__device__ __align__(16) __hip_bfloat16 g_Wp[86016];
__device__ float           g_stats[128];
__device__ float           g_coef[128];
__device__ int             g_isbf16;

__device__ __forceinline__ float loadf(const void* p, int i, bool bf)
{
    return bf ? (float)((const __hip_bfloat16*)p)[i] : ((const float*)p)[i];
}

// ---------------- wire dtype detection ----------------
__global__ void detect_kernel(const unsigned int* __restrict__ w)
{
    int cnt = 0;
    for (int i = 0; i < 256; ++i) {
        unsigned int lo = w[i] & 0xFFFFu;
        int ex = (int)((lo >> 7) & 0xFFu);
        if (lo == 0u || (ex >= 96 && ex <= 140)) cnt++;
    }
    g_isbf16 = (cnt >= 200) ? 1 : 0;
}

// ---------------- zero-init scratch ----------------
__global__ void init_kernel(int n)
{
    int i = blockIdx.x * blockDim.x + threadIdx.x;
    if (i < n) { g_deg[i] = 0; g_cursor[i] = 0; }
    if (i < 128) g_stats[i] = 0.0f;
}

// ---------------- per-edge basis + widx + degree count ----------------
__global__ void basis_kernel(const void* __restrict__ attr,
                             const int* __restrict__ dst, int E)
{
    int e = blockIdx.x * blockDim.x + threadIdx.x;
    if (e >= E) return;
    const bool bf = (g_isbf16 != 0);
    float f[3];
    int lo[3];
#pragma unroll
    for (int d = 0; d < 3; ++d) {
        float a = loadf(attr, e * 3 + d, bf);
        float s = a * 3.0f;
        float l = floorf(s);
        lo[d] = (int)l;
        f[d] = s - l;
    }
    const int p3[3] = {1, 3, 9};
#pragma unroll
    for (int b = 0; b < 8; ++b) {
        float w = 1.0f;
        int id = 0;
#pragma unroll
        for (int d = 0; d < 3; ++d) {
            int bit = (b >> d) & 1;
            w *= bit ? f[d] : (1.0f - f[d]);
            id += ((lo[d] + bit) % 3) * p3[d];
        }
        g_basis[e * 8 + b] = w;
        g_widx[e * 8 + b] = (unsigned char)id;
    }
    atomicAdd(&g_deg[dst[e]], 1);
}

// ---------------- exclusive scan (single block) ----------------
__global__ void scan_kernel(int n, int chunk)
{
    __shared__ int buf[1024];
    int tid = threadIdx.x;
    int begin = tid * chunk;
    int end = begin + chunk; if (end > n) end = n;
    int s = 0;
    for (int i = begin; i < end; ++i) s += g_deg[i];
    buf[tid] = s;
    __syncthreads();
    for (int o = 1; o < 1024; o <<= 1) {
        int t = (tid >= o) ? buf[tid - o] : 0;
        __syncthreads();
        buf[tid] += t;
        __syncthreads();
    }
    int base = buf[tid] - s;
    for (int i = begin; i < end; ++i) { g_offs[i] = base; base += g_deg[i]; }
    if (tid == 1023) g_offs[n] = buf[1023];
}

// ---------------- CSR fill ----------------
__global__ void fill_kernel(const int* __restrict__ dst, int E)
{
    int e = blockIdx.x * blockDim.x + threadIdx.x;
    if (e >= E) return;
    int d = dst[e];
    int p = atomicAdd(&g_cursor[d], 1);
    g_eidx[g_offs[d] + p] = e;
}

// ---------------- cast external x -> g_h0 bf16 ----------------
__global__ void cast_x(const void* __restrict__ x, int total)
{
    int t = blockIdx.x * blockDim.x + threadIdx.x;
    if (t >= total) return;
    g_h0[t] = __float2bfloat16(loadf(x, t, g_isbf16 != 0));
}

// ---------------- pack W+root into MFMA B-fragment order ----------------
// g_Wp[t], t = (((nt*KB)+kk)*64 + lane)*8 + j ; k = kk*32 + (lane>>4)*8 + j ;
// ncol = nt*16 + (lane&15) ; kw = ncol/COUT ; o = ncol%COUT
template <int CIN, int COUT, int KPAD>
__global__ void prep_w(const void* __restrict__ W, const void* __restrict__ root,
                       int total)
{
    int t = blockIdx.x * blockDim.x + threadIdx.x;
    if (t >= total) return;
    const bool bf = (g_isbf16 != 0);
    const int KB = KPAD / 32;
    int j = t & 7;
    int lane = (t >> 3) & 63;
    int rest = t >> 9;
    int kk = rest % KB;
    int nt = rest / KB;
    int k = kk * 32 + (lane >> 4) * 8 + j;
    int ncol = nt * 16 + (lane & 15);
    int kw = ncol / COUT;
    int o = ncol - kw * COUT;
    float v = 0.0f;
    if (k < CIN)
        v = (kw < 27) ? loadf(W, (kw * CIN + k) * COUT + o, bf)
                      : loadf(root, k * COUT + o, bf);
    g_Wp[t] = __float2bfloat16(v);
}

// ---------------- dense GEMM: Z = h @ Wp via MFMA 16x16x32 bf16 ----------------
// A[m][k]: m = lane&15, k = quad*8+j (16B contiguous per lane)
// B[k][n]: n = lane&15, k = quad*8+j (pre-packed in g_Wp)
// D: col(n) = lane&15, row(m) = quad*4+reg   [m89-verified]
template <int HSEL, int STRIDE, int NTOT, int KPAD, int NPW>
__global__ __launch_bounds__(256) void gemm_kernel(int MT, int NTW)
{
    int gid = blockIdx.x * 256 + threadIdx.x;
    int gw = gid >> 6, lane = gid & 63;
    if (gw >= MT * NTW) return;
    int mt = gw % MT;
    int ntb = (gw / MT) * NPW;
    const __hip_bfloat16* h = (HSEL == 0) ? g_h0 : (HSEL == 1) ? g_h1 : g_h3;
    int m = lane & 15, quad = lane >> 4;
    const short* hrow = (const short*)h + (size_t)(mt * 16 + m) * STRIDE;
    floatx4 acc[NPW] = {};
    const int KB = KPAD / 32;
#pragma unroll
    for (int kk = 0; kk < KB; ++kk) {
        short8 a = *(const short8*)(hrow + kk * 32 + quad * 8);
#pragma unroll
        for (int i = 0; i < NPW; ++i) {
            const short* bp = (const short*)g_Wp +
                (((size_t)(ntb + i) * KB + kk) * 64 + lane) * 8;
            short8 b = *(const short8*)bp;
            acc[i] = __builtin_amdgcn_mfma_f32_16x16x32_bf16(a, b, acc[i], 0, 0, 0);
        }
    }
    int col = lane & 15;
    int rowbase = mt * 16 + quad * 4;
#pragma unroll
    for (int i = 0; i < NPW; ++i) {
        int ncol = (ntb + i) * 16 + col;
#pragma unroll
        for (int r = 0; r < 4; ++r)
            g_Z[(size_t)(rowbase + r) * NTOT + ncol] = __float2bfloat16(acc[i][r]);
    }
}

// ---------------- aggregation: one wave per node, register-only ----------------
// OUT_SEL: 1 -> g_h1, 2 -> g_h2, 0 -> external (wire dtype)
template <int COUT, int NTOT, bool ELU, int OUT_SEL>
__global__ __launch_bounds__(256) void agg_kernel(const int* __restrict__ src,
                                                  const void* __restrict__ bias,
                                                  void* __restrict__ out_ext, int N)
{
    int wid = threadIdx.x >> 6, lane = threadIdx.x & 63;
    int n = blockIdx.x * 4 + wid;
    if (n >= N) return;
    const bool bf = (g_isbf16 != 0);
    int e0 = g_offs[n], e1 = g_offs[n + 1];
    float acc = 0.0f;
    if (COUT == 64) {
        int o = lane;
        for (int ei = e0; ei < e1; ++ei) {
            int e = g_eidx[ei];
            const __hip_bfloat16* zr = g_Z + (size_t)src[e] * NTOT;
#pragma unroll
            for (int b = 0; b < 8; ++b) {
                float bs = g_basis[e * 8 + b];
                int wx = (int)g_widx[e * 8 + b];
                acc += bs * (float)zr[wx * 64 + o];
            }
        }
    } else {
        int o = lane & 31, bh = lane >> 5;
        for (int ei = e0; ei < e1; ++ei) {
            int e = g_eidx[ei];
            const __hip_bfloat16* zr = g_Z + (size_t)src[e] * NTOT;
#pragma unroll
            for (int bi = 0; bi < 4; ++bi) {
                int b = bh + bi * 2;
                float bs = g_basis[e * 8 + b];
                int wx = (int)g_widx[e * 8 + b];
                acc += bs * (float)zr[wx * 32 + o];
            }
        }
        acc += __shfl_xor(acc, 32, 64);
        if (lane >= 32) return;
    }
    int o = (COUT == 64) ? lane : (lane & 31);
    int deg = e1 - e0;
    float inv = 1.0f / (float)(deg < 1 ? 1 : deg);
    float v = acc * inv + (float)g_Z[(size_t)n * NTOT + 27 * COUT + o]
            + loadf(bias, o, bf);
    if (ELU) v = v > 0.0f ? v : expm1f(v);
    if (OUT_SEL == 1)      g_h1[n * 32 + o] = __float2bfloat16(v);
    else if (OUT_SEL == 2) g_h2[n * 64 + o] = __float2bfloat16(v);
    else {
        if (bf) ((__hip_bfloat16*)out_ext)[n * COUT + o] = __float2bfloat16(v);
        else    ((float*)out_ext)[n * COUT + o] = v;
    }
}

// ---------------- BN stats ----------------
__global__ void bn_reduce(int n)
{
    int tid = threadIdx.x;
    int c = tid & 63;
    int r = tid >> 6;
    float s = 0.0f, s2 = 0.0f;
    for (int i = blockIdx.x * 4 + r; i < n; i += gridDim.x * 4) {
        float v = (float)g_h2[i * 64 + c];
        s += v; s2 += v * v;
    }
    __shared__ float b1s[256], b2s[256];
    b1s[tid] = s; b2s[tid] = s2;
    __syncthreads();
    if (r == 0) {
        s  = b1s[c] + b1s[c + 64] + b1s[c + 128] + b1s[c + 192];
        s2 = b2s[c] + b2s[c + 64] + b2s[c + 128] + b2s[c + 192];
        atomicAdd(&g_stats[c], s);
        atomicAdd(&g_stats[64 + c], s2);
    }
}

__global__ void bn_coef(const void* __restrict__ gamma,
                        const void* __restrict__ beta, int n)
{
    int c = threadIdx.x;
    const bool bf = (g_isbf16 != 0);
    float inv_n = 1.0f / (float)n;
    float mu = g_stats[c] * inv_n;
    float var = g_stats[64 + c] * inv_n - mu * mu;
    float A = rsqrtf(var + EPS) * loadf(gamma, c, bf);
    g_coef[c] = A;
    g_coef[64 + c] = loadf(beta, c, bf) - mu * A;
}

// ---------------- h3 = [elu(bn(h2)), pos, 0-pad] (96 ch) ----------------
__global__ void h3_build(const void* __restrict__ pos, int N)
{
    int t = blockIdx.x * blockDim.x + threadIdx.x;
    if (t >= N * 96) return;
    int n = t / 96, ch = t - n * 96;
    const bool bf = (g_isbf16 != 0);
    float v;
    if (ch < 64) {
        float h = (float)g_h2[n * 64 + ch];
        v = h * g_coef[ch] + g_coef[64 + ch];
        v = v > 0.0f ? v : expm1f(v);
    } else if (ch < 67) {
        v = loadf(pos, n * 3 + (ch - 64), bf);
    } else {
        v = 0.0f;
    }
    g_h3[(size_t)n * 96 + ch] = __float2bfloat16(v);
}

extern "C" void kernel_launch(void* const* d_in, const int* in_sizes, int n_in,
                              void* d_out, int out_size, void* d_ws, size_t ws_size,
                              hipStream_t stream)
{
    const void* x      = d_in[0];
    const int*  eindex = (const int*)d_in[1];
    const void* eattr  = d_in[2];
    const void* pos    = d_in[3];
    const void* W1     = d_in[4];
    const void* root1  = d_in[5];
    const void* b1     = d_in[6];
    const void* W2     = d_in[7];
    const void* root2  = d_in[8];
    const void* b2     = d_in[9];
    const void* gamma  = d_in[10];
    const void* beta   = d_in[11];
    const void* W3     = d_in[12];
    const void* root3  = d_in[13];
    const void* b3     = d_in[14];
    (void)d_ws; (void)ws_size; (void)n_in; (void)out_size;

    const int N = in_sizes[0] / 32;
    const int E = in_sizes[1] / 2;
    const int* srcp = eindex;
    const int* dstp = eindex + E;

    detect_kernel<<<1, 1, 0, stream>>>((const unsigned int*)x);
    init_kernel<<<(N + 255) / 256, 256, 0, stream>>>(N);

    int eb = (E + 255) / 256;
    basis_kernel<<<eb, 256, 0, stream>>>(eattr, dstp, E);
    int chunk = (N + 1023) / 1024;
    scan_kernel<<<1, 1024, 0, stream>>>(N, chunk);
    fill_kernel<<<eb, 256, 0, stream>>>(dstp, E);
    cast_x<<<(N * 32 + 255) / 256, 256, 0, stream>>>(x, N * 32);

    const int MT = (N + 15) / 16;   // 3125 node tiles

    // ---- conv1: h0(32) -> Z(896) -> h1(32), ELU ----
    {
        const int NTOT = 28 * 32, KPAD = 32, NPW = 4;
        int wtot = (NTOT / 16) * (KPAD / 32) * 512;   // 28672
        prep_w<32, 32, KPAD><<<(wtot + 255) / 256, 256, 0, stream>>>(W1, root1, wtot);
        int NTW = (NTOT / 16) / NPW;                  // 14
        int waves = MT * NTW;
        gemm_kernel<0, 32, NTOT, KPAD, NPW><<<(waves + 3) / 4, 256, 0, stream>>>(MT, NTW);
        agg_kernel<32, NTOT, true, 1><<<(N + 3) / 4, 256, 0, stream>>>(srcp, b1, nullptr, N);
    }
    // ---- conv2: h1(32) -> Z(1792) -> h2(64), raw ----
    {
        const int NTOT = 28 * 64, KPAD = 32, NPW = 4;
        int wtot = (NTOT / 16) * (KPAD / 32) * 512;   // 57344
        prep_w<32, 64, KPAD><<<(wtot + 255) / 256, 256, 0, stream>>>(W2, root2, wtot);
        int NTW = (NTOT / 16) / NPW;                  // 28
        int waves = MT * NTW;
        gemm_kernel<1, 32, NTOT, KPAD, NPW><<<(waves + 3) / 4, 256, 0, stream>>>(MT, NTW);
        agg_kernel<64, NTOT, false, 2><<<(N + 3) / 4, 256, 0, stream>>>(srcp, b2, nullptr, N);
    }
    // ---- BN + h3 build ----
    bn_reduce<<<120, 256, 0, stream>>>(N);
    bn_coef<<<1, 64, 0, stream>>>(gamma, beta, N);
    h3_build<<<(N * 96 + 255) / 256, 256, 0, stream>>>(pos, N);
    // ---- conv3: h3(96, padded from 67) -> Z(896) -> out(32), raw ----
    {
        const int NTOT = 28 * 32, KPAD = 96, NPW = 4;
        int wtot = (NTOT / 16) * (KPAD / 32) * 512;   // 86016
        prep_w<67, 32, KPAD><<<(wtot + 255) / 256, 256, 0, stream>>>(W3, root3, wtot);
        int NTW = (NTOT / 16) / NPW;                  // 14
        int waves = MT * NTW;
        gemm_kernel<2, 96, NTOT, KPAD, NPW><<<(waves + 3) / 4, 256, 0, stream>>>(MT, NTW);
        agg_kernel<32, NTOT, false, 0><<<(N + 3) / 4, 256, 0, stream>>>(srcp, b3, d_out, N);
    }
}